// Round 7
// baseline (40.633 us; speedup 1.0000x reference)
//
#include <hip/hip_runtime.h>
#include <hip/hip_fp16.h>
#include <math.h>

#define NUM_CLASSES 200
#define NUM_PROTO   10
#define EMBED_D     512
#define NTOK        8192
#define INV_EPS     100.0f
#define EPSF        0.01f
#define MOM         0.02f
#define ITERS       5
#define CAPJ        96      // max class size (binomial mu=41 sigma=6.4; +8.6 sigma)

__device__ __forceinline__ float wave_sum(float v) {
#pragma unroll
    for (int o = 32; o; o >>= 1) v += __shfl_xor(v, o);
    return v;
}
__device__ __forceinline__ float wave_max(float v) {
#pragma unroll
    for (int o = 32; o; o >>= 1) v = fmaxf(v, __shfl_xor(v, o));
    return v;
}

// ---- single fused kernel: one block per class does EVERYTHING -------------
// phase 0: class-local count + stable rank of own tokens (scan, no atomics)
// phase 1: normalized tokens -> LDS (f16) + similarities S[10][cnt] (2-deep
//          software-pipelined token loads)
// phase 2: Sinkhorn, wave-parallel rows / thread-parallel cols
// phase 3: accumulate from LDS tokens; wave w owns dims [w*32,+32),
//          lane&31 = dim, lane>>5 = j parity; register accumulators
// phase 4: blend + cross-wave sumsq + L2 normalize + write
__global__ __launch_bounds__(1024) void k_all(
        const float* __restrict__ tokens,
        const int*   __restrict__ labels,
        const float* __restrict__ protos,
        float*       __restrict__ out) {
    __shared__ __align__(16) __half tok_sh[CAPJ][EMBED_D]; // 96 KB, normalized
    __shared__ float S_sh[NUM_PROTO][CAPJ];    // 3.75 KB (later: weights)
    __shared__ float v_sh[CAPJ];
    __shared__ float u_sh[NUM_PROTO];
    __shared__ float ss_part[16][NUM_PROTO];
    __shared__ float tot_sh[NUM_PROTO];
    __shared__ int   idx_l[CAPJ];
    __shared__ int   weq[16];

    const int c    = blockIdx.x;
    const int tid  = threadIdx.x;
    const int lane = tid & 63;
    const int wave = tid >> 6;

    // ---- phase 0: each thread owns 8 consecutive labels; scan ranks -------
    int4 la = *(const int4*)(labels + tid * 8);
    int4 lb = *(const int4*)(labels + tid * 8 + 4);
    int l[8] = {la.x, la.y, la.z, la.w, lb.x, lb.y, lb.z, lb.w};
    int meq = 0;
#pragma unroll
    for (int i = 0; i < 8; ++i) meq += (l[i] == c);
    int incl = meq;
#pragma unroll
    for (int o = 1; o < 64; o <<= 1) { int t = __shfl_up(incl, o); if (lane >= o) incl += t; }
    if (lane == 63) weq[wave] = incl;
    if (tid < CAPJ) v_sh[tid] = 0.0f;
    __syncthreads();
    int cnt = 0, wbase = 0;
#pragma unroll
    for (int w = 0; w < 16; ++w) { int q = weq[w]; cnt += q; if (w < wave) wbase += q; }
    if (cnt > CAPJ) cnt = CAPJ;                // unreachable memory-safety clamp
    int pos = wbase + incl - meq;
#pragma unroll
    for (int i = 0; i < 8; ++i)
        if (l[i] == c && pos < CAPJ) { idx_l[pos] = tid * 8 + i; ++pos; }
    __syncthreads();

    // ---- phase 1: sims + normalized f16 tokens to LDS (pipelined loads) ---
    {
        const int wp = wave >> 1, ph = wave & 1;   // 8 wave-pairs, 5 protos each
        float preg[5][8];
        const float* pb = protos + (size_t)(c * NUM_PROTO + ph * 5) * EMBED_D + lane * 8;
#pragma unroll
        for (int p = 0; p < 5; ++p) {
            float4 x = *(const float4*)(pb + p * EMBED_D);
            float4 y = *(const float4*)(pb + p * EMBED_D + 4);
            preg[p][0]=x.x; preg[p][1]=x.y; preg[p][2]=x.z; preg[p][3]=x.w;
            preg[p][4]=y.x; preg[p][5]=y.y; preg[p][6]=y.z; preg[p][7]=y.w;
        }
        int j = wp;
        float4 ta, tb;
        if (j < cnt) {
            const float* tr = tokens + (size_t)idx_l[j] * EMBED_D + lane * 8;
            ta = *(const float4*)tr;
            tb = *(const float4*)(tr + 4);
        }
        while (j < cnt) {
            int j2 = j + 8;
            float4 na, nb;
            if (j2 < cnt) {                      // prefetch next token row
                const float* tr = tokens + (size_t)idx_l[j2] * EMBED_D + lane * 8;
                na = *(const float4*)tr;
                nb = *(const float4*)(tr + 4);
            }
            float ssq = ta.x*ta.x + ta.y*ta.y + ta.z*ta.z + ta.w*ta.w
                      + tb.x*tb.x + tb.y*tb.y + tb.z*tb.z + tb.w*tb.w;
            ssq = wave_sum(ssq);
            float inv = 1.0f / sqrtf(ssq);
            ta.x*=inv; ta.y*=inv; ta.z*=inv; ta.w*=inv;
            tb.x*=inv; tb.y*=inv; tb.z*=inv; tb.w*=inv;
            if (ph == 0) {                       // store normalized f16 row
                float4 pack;
                __half2* hp = (__half2*)&pack;
                hp[0] = __floats2half2_rn(ta.x, ta.y);
                hp[1] = __floats2half2_rn(ta.z, ta.w);
                hp[2] = __floats2half2_rn(tb.x, tb.y);
                hp[3] = __floats2half2_rn(tb.z, tb.w);
                *(float4*)&tok_sh[j][lane * 8] = pack;
            }
#pragma unroll
            for (int p = 0; p < 5; ++p) {
                float d = preg[p][0]*ta.x + preg[p][1]*ta.y + preg[p][2]*ta.z + preg[p][3]*ta.w
                        + preg[p][4]*tb.x + preg[p][5]*tb.y + preg[p][6]*tb.z + preg[p][7]*tb.w;
                d = wave_sum(d);
                if (lane == 0) S_sh[ph * 5 + p][j] = d;
            }
            ta = na; tb = nb; j = j2;
        }
    }
    __syncthreads();

    // ---- phase 2: Sinkhorn (wave p: row LSE over j; thread j: col LSE) ----
    const float log_a = -2.3025850f;           // log(0.1 + 1e-8)
    const float log_b = __logf(1.0f / (float)(cnt > 0 ? cnt : 1) + 1e-8f);
    for (int it = 0; it < ITERS; ++it) {
        if (wave < NUM_PROTO) {
            int j1 = lane + 64;
            float x0 = (lane < cnt) ? (S_sh[wave][lane] + v_sh[lane]) * INV_EPS : -1e30f;
            float x1 = (j1  < cnt) ? (S_sh[wave][j1]  + v_sh[j1])  * INV_EPS : -1e30f;
            float M  = wave_max(fmaxf(x0, x1));
            float sm = wave_sum(__expf(x0 - M) + __expf(x1 - M));
            if (lane == 0) u_sh[wave] = EPSF * (log_a - (M + __logf(sm)));
        }
        __syncthreads();
        if (tid < cnt) {
            float x[NUM_PROTO], m = -1e30f;
#pragma unroll
            for (int p = 0; p < NUM_PROTO; ++p) {
                x[p] = (S_sh[p][tid] + u_sh[p]) * INV_EPS;
                m = fmaxf(m, x[p]);
            }
            float sm = 0.0f;
#pragma unroll
            for (int p = 0; p < NUM_PROTO; ++p) sm += __expf(x[p] - m);
            v_sh[tid] = EPSF * (log_b - (m + __logf(sm)));
        }
        __syncthreads();
    }
    // weights w[p][j] = pi / colsum (tokens in LDS already normalized)
    if (tid < cnt) {
        float vj = v_sh[tid];
        float e[NUM_PROTO], cs = 0.0f;
#pragma unroll
        for (int p = 0; p < NUM_PROTO; ++p) {
            e[p] = __expf((S_sh[p][tid] + u_sh[p] + vj) * INV_EPS);
            cs += e[p];
        }
        float sc = 1.0f / cs;
#pragma unroll
        for (int p = 0; p < NUM_PROTO; ++p) S_sh[p][tid] = e[p] * sc;
    }
    __syncthreads();

    // ---- phase 3: accumulate from LDS; wave owns 32 dims, lanes split j ---
    const int d  = wave * 32 + (lane & 31);    // this thread's dim
    const int h  = lane >> 5;                  // j parity
    float acc[NUM_PROTO];
#pragma unroll
    for (int p = 0; p < NUM_PROTO; ++p) acc[p] = 0.0f;
    for (int j = h; j < cnt; j += 2) {
        float t = __half2float(tok_sh[j][d]);
#pragma unroll
        for (int p = 0; p < NUM_PROTO; ++p)
            acc[p] += S_sh[p][j] * t;          // S broadcast (2-way, free)
    }
#pragma unroll
    for (int p = 0; p < NUM_PROTO; ++p)
        acc[p] += __shfl_xor(acc[p], 32);      // merge j parities (same dim)

    // ---- phase 4: blend + cross-wave sumsq + normalize + write ------------
    float o[NUM_PROTO];
#pragma unroll
    for (int p = 0; p < NUM_PROTO; ++p) {
        int row = c * NUM_PROTO + p;
        float pr = protos[(size_t)row * EMBED_D + d];
        o[p] = (1.0f - MOM) * pr + MOM * acc[p];
        float ps = wave_sum((h == 0) ? o[p] * o[p] : 0.0f);
        if (lane == 0) ss_part[wave][p] = ps;
    }
    __syncthreads();
    if (wave == 0 && lane < NUM_PROTO) {
        float s = 0.0f;
#pragma unroll
        for (int w = 0; w < 16; ++w) s += ss_part[w][lane];
        tot_sh[lane] = s;
    }
    __syncthreads();
    if (h == 0) {
#pragma unroll
        for (int p = 0; p < NUM_PROTO; ++p) {
            float invn = 1.0f / sqrtf(tot_sh[p]);
            int row = c * NUM_PROTO + p;
            out[(size_t)row * EMBED_D + d] = o[p] * invn;
        }
    }
}

extern "C" void kernel_launch(void* const* d_in, const int* in_sizes, int n_in,
                              void* d_out, int out_size, void* d_ws, size_t ws_size,
                              hipStream_t stream) {
    const float* tokens = (const float*)d_in[0];
    const int*   labels = (const int*)d_in[1];
    const float* protos = (const float*)d_in[2];
    float* out = (float*)d_out;
    (void)d_ws; (void)ws_size; (void)in_sizes; (void)n_in; (void)out_size;

    k_all<<<NUM_CLASSES, 1024, 0, stream>>>(tokens, labels, protos, out);
}

// Round 8
// 33.927 us; speedup vs baseline: 1.1976x; 1.1976x over previous
//
#include <hip/hip_runtime.h>
#include <math.h>

#define NUM_CLASSES 200
#define NUM_PROTO   10
#define EMBED_D     512
#define NTOK        8192
#define INV_EPS     100.0f
#define EPSF        0.01f
#define MOM         0.02f
#define ITERS       5
#define CAPJ        128     // max class size (binomial mu=41 sigma=6.4; +13.6 sigma)

__device__ __forceinline__ float wave_sum(float v) {
#pragma unroll
    for (int o = 32; o; o >>= 1) v += __shfl_xor(v, o);
    return v;
}
__device__ __forceinline__ float wave_max(float v) {
#pragma unroll
    for (int o = 32; o; o >>= 1) v = fmaxf(v, __shfl_xor(v, o));
    return v;
}

// ---- single fused kernel: one block per class does EVERYTHING -------------
// phase 0: class-local count + stable rank of own tokens (scan, no atomics)
// phase 1: similarities S[10][cnt] into LDS (wave-pairs: 5 protos each,
//          1-deep token-row prefetch)
// phase 2: Sinkhorn; final v-update dropped (cancels in pi/pi.sum(0):
//          weights = softmax_p((S+u)/eps) * inv_norm)
// phase 3: accumulate new_proto (16 waves = 4 dimgroups x 4 j-slices)
// phase 4: reduce + momentum blend; phase 5: L2 normalize + write
__global__ __launch_bounds__(1024) void k_all(
        const float* __restrict__ tokens,
        const int*   __restrict__ labels,
        const float* __restrict__ protos,
        float*       __restrict__ out) {
    __shared__ float S_sh[NUM_PROTO][CAPJ];    // 5 KB
    __shared__ float red[16][NUM_PROTO][128];  // 80 KB
    __shared__ float o_sh[NUM_PROTO][EMBED_D]; // 20 KB
    __shared__ float v_sh[CAPJ];
    __shared__ float inv_l[CAPJ];
    __shared__ float u_sh[NUM_PROTO];
    __shared__ int   idx_l[CAPJ];
    __shared__ int   weq[16];

    const int c    = blockIdx.x;
    const int tid  = threadIdx.x;
    const int lane = tid & 63;
    const int wave = tid >> 6;

    // ---- phase 0: each thread owns 8 consecutive labels; scan ranks -------
    int4 la = *(const int4*)(labels + tid * 8);
    int4 lb = *(const int4*)(labels + tid * 8 + 4);
    int l[8] = {la.x, la.y, la.z, la.w, lb.x, lb.y, lb.z, lb.w};
    int meq = 0;
#pragma unroll
    for (int i = 0; i < 8; ++i) meq += (l[i] == c);
    int incl = meq;
#pragma unroll
    for (int o = 1; o < 64; o <<= 1) { int t = __shfl_up(incl, o); if (lane >= o) incl += t; }
    if (lane == 63) weq[wave] = incl;
    if (tid < CAPJ) v_sh[tid] = 0.0f;
    __syncthreads();
    int cnt = 0, wbase = 0;
#pragma unroll
    for (int w = 0; w < 16; ++w) { int q = weq[w]; cnt += q; if (w < wave) wbase += q; }
    if (cnt > CAPJ) cnt = CAPJ;                // unreachable memory-safety clamp
    int pos = wbase + incl - meq;
#pragma unroll
    for (int i = 0; i < 8; ++i)
        if (l[i] == c && pos < CAPJ) { idx_l[pos] = tid * 8 + i; ++pos; }
    __syncthreads();

    // ---- phase 1: similarities; wave-pair wp: token j, 5 protos; prefetch -
    {
        const int wp = wave >> 1, ph = wave & 1;
        float preg[5][8];
        const float* pb = protos + (size_t)(c * NUM_PROTO + ph * 5) * EMBED_D + lane * 8;
#pragma unroll
        for (int p = 0; p < 5; ++p) {
            float4 x = *(const float4*)(pb + p * EMBED_D);
            float4 y = *(const float4*)(pb + p * EMBED_D + 4);
            preg[p][0]=x.x; preg[p][1]=x.y; preg[p][2]=x.z; preg[p][3]=x.w;
            preg[p][4]=y.x; preg[p][5]=y.y; preg[p][6]=y.z; preg[p][7]=y.w;
        }
        int j = wp;
        float4 ta, tb;
        if (j < cnt) {
            const float* tr = tokens + (size_t)idx_l[j] * EMBED_D + lane * 8;
            ta = *(const float4*)tr;
            tb = *(const float4*)(tr + 4);
        }
        while (j < cnt) {
            int j2 = j + 8;
            float4 na, nb;
            if (j2 < cnt) {                      // prefetch next token row
                const float* tr = tokens + (size_t)idx_l[j2] * EMBED_D + lane * 8;
                na = *(const float4*)tr;
                nb = *(const float4*)(tr + 4);
            }
            float ssq = ta.x*ta.x + ta.y*ta.y + ta.z*ta.z + ta.w*ta.w
                      + tb.x*tb.x + tb.y*tb.y + tb.z*tb.z + tb.w*tb.w;
            ssq = wave_sum(ssq);
            float inv = 1.0f / sqrtf(ssq);
            if (ph == 0 && lane == 0) inv_l[j] = inv;
#pragma unroll
            for (int p = 0; p < 5; ++p) {
                float d = preg[p][0]*ta.x + preg[p][1]*ta.y + preg[p][2]*ta.z + preg[p][3]*ta.w
                        + preg[p][4]*tb.x + preg[p][5]*tb.y + preg[p][6]*tb.z + preg[p][7]*tb.w;
                d = wave_sum(d);
                if (lane == 0) S_sh[ph * 5 + p][j] = d * inv;
            }
            ta = na; tb = nb; j = j2;
        }
    }
    __syncthreads();

    // ---- phase 2: Sinkhorn (wave p: row LSE; thread j: col LSE) -----------
    const float log_a = -2.3025850f;           // log(0.1 + 1e-8)
    const float log_b = __logf(1.0f / (float)(cnt > 0 ? cnt : 1) + 1e-8f);
    for (int it = 0; it < ITERS; ++it) {
        if (wave < NUM_PROTO) {
            int j1 = lane + 64;
            float x0 = (lane < cnt) ? (S_sh[wave][lane] + v_sh[lane]) * INV_EPS : -1e30f;
            float x1 = (j1  < cnt) ? (S_sh[wave][j1]  + v_sh[j1])  * INV_EPS : -1e30f;
            float M  = wave_max(fmaxf(x0, x1));
            float sm = wave_sum(__expf(x0 - M) + __expf(x1 - M));
            if (lane == 0) u_sh[wave] = EPSF * (log_a - (M + __logf(sm)));
        }
        __syncthreads();
        if (it < ITERS - 1) {                  // final v-update cancels in pi/colsum
            if (tid < cnt) {
                float x[NUM_PROTO], m = -1e30f;
#pragma unroll
                for (int p = 0; p < NUM_PROTO; ++p) {
                    x[p] = (S_sh[p][tid] + u_sh[p]) * INV_EPS;
                    m = fmaxf(m, x[p]);
                }
                float sm = 0.0f;
#pragma unroll
                for (int p = 0; p < NUM_PROTO; ++p) sm += __expf(x[p] - m);
                v_sh[tid] = EPSF * (log_b - (m + __logf(sm)));
            }
            __syncthreads();
        }
    }
    // weights w[p][j] = softmax_p((S+u)/eps) * inv_norm  (v cancels exactly)
    if (tid < cnt) {
        float x[NUM_PROTO], m = -1e30f;
#pragma unroll
        for (int p = 0; p < NUM_PROTO; ++p) {
            x[p] = (S_sh[p][tid] + u_sh[p]) * INV_EPS;
            m = fmaxf(m, x[p]);
        }
        float e[NUM_PROTO], cs = 0.0f;
#pragma unroll
        for (int p = 0; p < NUM_PROTO; ++p) { e[p] = __expf(x[p] - m); cs += e[p]; }
        float sc = inv_l[tid] / cs;
#pragma unroll
        for (int p = 0; p < NUM_PROTO; ++p) S_sh[p][tid] = e[p] * sc;
    }
    __syncthreads();

    // ---- phase 3: accumulate; wave (g,js): dims [g*128,+128), j += 4 ------
    const int g  = wave >> 2, js = wave & 3;
    const int d0 = g * 128 + lane * 2;
    float acc[NUM_PROTO][2];
#pragma unroll
    for (int p = 0; p < NUM_PROTO; ++p) { acc[p][0] = 0.0f; acc[p][1] = 0.0f; }
    for (int j = js; j < cnt; j += 4) {
        int n = idx_l[j];
        float2 t = *(const float2*)(tokens + (size_t)n * EMBED_D + d0);
#pragma unroll
        for (int p = 0; p < NUM_PROTO; ++p) {
            float w = S_sh[p][j];              // LDS broadcast
            acc[p][0] += w * t.x;
            acc[p][1] += w * t.y;
        }
    }
#pragma unroll
    for (int p = 0; p < NUM_PROTO; ++p)
        *(float2*)&red[wave][p][lane * 2] = make_float2(acc[p][0], acc[p][1]);
    __syncthreads();

    // ---- phase 4: reduce j-slices + momentum blend ------------------------
    for (int e4 = tid; e4 < NUM_PROTO * EMBED_D; e4 += 1024) {
        int p  = e4 >> 9;
        int d  = e4 & 511;
        int gg = d >> 7;
        int dd = d & 127;
        float s = red[gg * 4 + 0][p][dd] + red[gg * 4 + 1][p][dd]
                + red[gg * 4 + 2][p][dd] + red[gg * 4 + 3][p][dd];
        int row = c * NUM_PROTO + p;
        o_sh[p][d] = (1.0f - MOM) * protos[(size_t)row * EMBED_D + d] + MOM * s;
    }
    __syncthreads();

    // ---- phase 5: per-row L2 normalize + write ----------------------------
    if (wave < NUM_PROTO) {
        const float* orow = &o_sh[wave][0];
        float4 a = *(const float4*)(orow + lane * 8);
        float4 b = *(const float4*)(orow + lane * 8 + 4);
        float ss = a.x*a.x + a.y*a.y + a.z*a.z + a.w*a.w
                 + b.x*b.x + b.y*b.y + b.z*b.z + b.w*b.w;
        ss = wave_sum(ss);
        float inv = 1.0f / sqrtf(ss);
        int row = c * NUM_PROTO + wave;
        float* od = out + (size_t)row * EMBED_D + lane * 8;
        float4 w0 = make_float4(a.x*inv, a.y*inv, a.z*inv, a.w*inv);
        float4 w1 = make_float4(b.x*inv, b.y*inv, b.z*inv, b.w*inv);
        *(float4*)od       = w0;
        *(float4*)(od + 4) = w1;
    }
}

extern "C" void kernel_launch(void* const* d_in, const int* in_sizes, int n_in,
                              void* d_out, int out_size, void* d_ws, size_t ws_size,
                              hipStream_t stream) {
    const float* tokens = (const float*)d_in[0];
    const int*   labels = (const int*)d_in[1];
    const float* protos = (const float*)d_in[2];
    float* out = (float*)d_out;
    (void)d_ws; (void)ws_size; (void)in_sizes; (void)n_in; (void)out_size;

    k_all<<<NUM_CLASSES, 1024, 0, stream>>>(tokens, labels, protos, out);
}